// Round 2
// baseline (121.541 us; speedup 1.0000x reference)
//
#include <hip/hip_runtime.h>
#include <hip/hip_bf16.h>
#include <stdint.h>

// ---------------------------------------------------------------------------
// MultiHeadedSelfAttention: x[2,2048,1024] -> out[2,2048,1024] (fp32)
// prep(bf16, W^T, rope table) -> fused QKV GEMM (bf16 MFMA) -> bias+RoPE
// epilogues -> banded flash attention (KVBLK=64, reg-staged dbuf, fast-path
// masks, XCD-grouped bh).
// ---------------------------------------------------------------------------

typedef __attribute__((ext_vector_type(8))) short bf16x8;
typedef __attribute__((ext_vector_type(4))) short bf16x4;
typedef __attribute__((ext_vector_type(4))) float f32x4;

#define DEV __device__ __forceinline__

DEV ushort f2b(float f) {               // fp32 -> bf16 bits, round-nearest-even
  union { float f; uint32_t u; } v; v.f = f;
  uint32_t r = v.u + 0x7FFFu + ((v.u >> 16) & 1u);
  return (ushort)(r >> 16);
}
DEV float b2f(ushort u) {
  union { uint32_t u; float f; } v; v.u = ((uint32_t)u) << 16;
  return v.f;
}

DEV void gload_lds16(const void* g, void* l) {
  __builtin_amdgcn_global_load_lds((const __attribute__((address_space(1))) void*)g,
                                   (__attribute__((address_space(3))) void*)l,
                                   16, 0, 0);
}

// ---------------------------------------------------------------------------
__global__ __launch_bounds__(256) void prep_x_kernel(const float* __restrict__ x,
                                                     ushort* __restrict__ xb) {
  int t = blockIdx.x * 256 + threadIdx.x;
  float4 v = ((const float4*)x)[t];
  bf16x4 o;
  o[0] = (short)f2b(v.x); o[1] = (short)f2b(v.y);
  o[2] = (short)f2b(v.z); o[3] = (short)f2b(v.w);
  *(bf16x4*)&xb[(size_t)t * 4] = o;
}

__global__ void prep_w_kernel(const float* __restrict__ wq, const float* __restrict__ wk,
                              const float* __restrict__ wv, ushort* __restrict__ wt) {
  __shared__ float tile[32][33];
  int which = blockIdx.z;
  const float* w = which == 0 ? wq : (which == 1 ? wk : wv);
  int n0 = blockIdx.x * 32, k0 = blockIdx.y * 32;
  tile[threadIdx.y][threadIdx.x] = w[(size_t)(k0 + threadIdx.y) * 1024 + n0 + threadIdx.x];
  __syncthreads();
  wt[((size_t)which * 1024 + n0 + threadIdx.y) * 1024 + k0 + threadIdx.x] =
      f2b(tile[threadIdx.x][threadIdx.y]);
}

__global__ __launch_bounds__(256) void rope_tab_kernel(float2* __restrict__ tab) {
  int t = blockIdx.x * 256 + threadIdx.x;          // 65536
  int i = t & 31, s = t >> 5;
  float theta = powf(10000.0f, -(float)i / 32.0f);
  float ang = (float)s * theta;
  tab[t] = make_float2(cosf(ang), sinf(ang));
}

// ---------------------------------------------------------------------------
// QKV GEMM: A = xb [4096][1024], Bt = wt [3072][1024] -> C bf16 [4096][3072]
__global__ __launch_bounds__(256) void qkv_gemm_kernel(const ushort* __restrict__ A,
                                                       const ushort* __restrict__ Bt,
                                                       ushort* __restrict__ C) {
  const int K = 1024, N = 3072;
  __shared__ alignas(16) ushort sA[2][128 * 32];
  __shared__ alignas(16) ushort sB[2][128 * 32];
  int tid = threadIdx.x;
  int bm = blockIdx.x, bn = blockIdx.y;
  int lane = tid & 63, wid = tid >> 6;
  int lhi = lane >> 4, llo = lane & 15;
  int wr = wid >> 1, wc = wid & 1;

  const ushort* Abase = A + (size_t)bm * 128 * K;
  const ushort* Bbase = Bt + (size_t)bn * 128 * K;

  f32x4 acc[4][4];
#pragma unroll
  for (int i = 0; i < 4; ++i)
#pragma unroll
    for (int j = 0; j < 4; ++j) acc[i][j] = (f32x4){0.f, 0.f, 0.f, 0.f};

  auto stage = [&](int kt, int buf) {
    int k0 = kt * 32;
#pragma unroll
    for (int c = 0; c < 2; ++c) {
      int idx = c * 256 + tid;
      int row = idx >> 2, col = (idx & 3) * 8;
      gload_lds16(Abase + (size_t)row * K + k0 + col, &sA[buf][(idx & ~63) * 8]);
      gload_lds16(Bbase + (size_t)row * K + k0 + col, &sB[buf][(idx & ~63) * 8]);
    }
  };

  stage(0, 0);
  for (int kt = 0; kt < 32; ++kt) {
    __syncthreads();
    if (kt + 1 < 32) stage(kt + 1, (kt + 1) & 1);
    int buf = kt & 1;
    bf16x8 af[4], bfr[4];
#pragma unroll
    for (int mf = 0; mf < 4; ++mf)
      af[mf] = *(const bf16x8*)&sA[buf][(wr * 64 + mf * 16 + llo) * 32 + lhi * 8];
#pragma unroll
    for (int nf = 0; nf < 4; ++nf)
      bfr[nf] = *(const bf16x8*)&sB[buf][(wc * 64 + nf * 16 + llo) * 32 + lhi * 8];
#pragma unroll
    for (int mf = 0; mf < 4; ++mf)
#pragma unroll
      for (int nf = 0; nf < 4; ++nf)
        acc[mf][nf] = __builtin_amdgcn_mfma_f32_16x16x32_bf16(af[mf], bfr[nf], acc[mf][nf], 0, 0, 0);
  }
#pragma unroll
  for (int mf = 0; mf < 4; ++mf)
#pragma unroll
    for (int nf = 0; nf < 4; ++nf)
#pragma unroll
      for (int j = 0; j < 4; ++j) {
        int row = bm * 128 + wr * 64 + mf * 16 + lhi * 4 + j;
        int col = bn * 128 + wc * 64 + nf * 16 + llo;
        C[(size_t)row * N + col] = f2b(acc[mf][nf][j]);
      }
}

// ---------------------------------------------------------------------------
// epilogue: bias + RoPE, vectorized 8 elems/thread. q pre-scaled by 0.125.
__global__ __launch_bounds__(256) void epi_qk_kernel(const ushort* __restrict__ C,
    const float* __restrict__ bq, const float* __restrict__ bk,
    const float2* __restrict__ tab,
    ushort* __restrict__ qb, ushort* __restrict__ kb) {
  int t = blockIdx.x * 256 + threadIdx.x;          // 4096*128
  int m = t >> 7, pp = (t & 127) << 3;
  int s = m & 2047;
  int h = pp >> 6, i0 = (pp & 63) >> 1;
  size_t crow = (size_t)m * 3072;
  bf16x8 qv = *(const bf16x8*)&C[crow + pp];
  bf16x8 kv = *(const bf16x8*)&C[crow + 1024 + pp];
  float4 bq0 = *(const float4*)&bq[pp], bq1 = *(const float4*)&bq[pp + 4];
  float4 bk0 = *(const float4*)&bk[pp], bk1 = *(const float4*)&bk[pp + 4];
  float4 cs01 = *(const float4*)&tab[s * 32 + i0];
  float4 cs23 = *(const float4*)&tab[s * 32 + i0 + 2];
  float cth[4] = {cs01.x, cs01.z, cs23.x, cs23.z};
  float sth[4] = {cs01.y, cs01.w, cs23.y, cs23.w};
  float bqa[8] = {bq0.x, bq0.y, bq0.z, bq0.w, bq1.x, bq1.y, bq1.z, bq1.w};
  float bka[8] = {bk0.x, bk0.y, bk0.z, bk0.w, bk1.x, bk1.y, bk1.z, bk1.w};
  bf16x8 qo, ko;
#pragma unroll
  for (int e = 0; e < 4; ++e) {
    float t0 = b2f((ushort)qv[2 * e])     + bqa[2 * e];
    float t1 = b2f((ushort)qv[2 * e + 1]) + bqa[2 * e + 1];
    qo[2 * e]     = (short)f2b((t0 * cth[e] - t1 * sth[e]) * 0.125f);
    qo[2 * e + 1] = (short)f2b((t1 * cth[e] + t0 * sth[e]) * 0.125f);
    float u0 = b2f((ushort)kv[2 * e])     + bka[2 * e];
    float u1 = b2f((ushort)kv[2 * e + 1]) + bka[2 * e + 1];
    ko[2 * e]     = (short)f2b(u0 * cth[e] - u1 * sth[e]);
    ko[2 * e + 1] = (short)f2b(u1 * cth[e] + u0 * sth[e]);
  }
  int bh = (m >> 11) * 16 + h;
  size_t ooff = ((size_t)bh * 2048 + s) * 64 + (pp & 63);
  *(bf16x8*)&qb[ooff] = qo;
  *(bf16x8*)&kb[ooff] = ko;
}

// epilogue: bias + transpose for v -> vt [32][64][2048] bf16
__global__ __launch_bounds__(256) void epi_v_kernel(const ushort* __restrict__ C,
    const float* __restrict__ bv, ushort* __restrict__ vt) {
  __shared__ float lv[64][65];
  int bh = blockIdx.y; int h = bh & 15;
  int s0 = blockIdx.x * 64;
  int tid = threadIdx.x;
  size_t mbase = (size_t)(bh >> 4) * 2048 + s0;
#pragma unroll
  for (int ph = 0; ph < 2; ++ph) {
    int idx = ph * 256 + tid;
    int row = idx >> 3, col = (idx & 7) * 8;
    bf16x8 v = *(const bf16x8*)&C[(mbase + row) * 3072 + 2048 + h * 64 + col];
#pragma unroll
    for (int e = 0; e < 8; ++e) lv[row][col + e] = b2f((ushort)v[e]);
  }
  __syncthreads();
#pragma unroll
  for (int ph = 0; ph < 2; ++ph) {
    int idx = ph * 256 + tid;
    int hd = idx >> 3, s8 = (idx & 7) * 8;
    float bias = bv[h * 64 + hd];
    bf16x8 o;
#pragma unroll
    for (int e = 0; e < 8; ++e) o[e] = (short)f2b(lv[s8 + e][hd] + bias);
    *(bf16x8*)&vt[((size_t)bh * 64 + hd) * 2048 + s0 + s8] = o;
  }
}

// ---------------------------------------------------------------------------
// banded flash attention. 1-D grid 1024, XCD-grouped bh. 4 waves x 16 q-rows,
// KVBLK=64, reg-staged double-buffer, wave-uniform fast-path masks.
__global__ __launch_bounds__(256) void attn_kernel(
    const ushort* __restrict__ qb, const ushort* __restrict__ kb,
    const ushort* __restrict__ vt, const int* __restrict__ kmask,
    const int* __restrict__ whist, float* __restrict__ out) {
  __shared__ alignas(16) ushort sK[64 * 64];       // [64 keys][64 hd], XOR-swizzled
  __shared__ alignas(16) ushort sV[64 * 72];       // [64 d][64 keys], pitch 72
  __shared__ alignas(16) ushort sP[4][16 * 72];    // per-wave [16 q][64 k], pitch 72

  int tid = threadIdx.x;
  int lane = tid & 63, wid = tid >> 6;
  int lhi = lane >> 4, llo = lane & 15;

  int id = blockIdx.x;
  int xcd = id & 7, sub = id >> 3;                 // group same-bh blocks per XCD (T1)
  int bh = xcd * 4 + (sub >> 5);
  int qtile = sub & 31;
  int b = bh >> 4;
  int q0 = qtile * 64;
  int qw0 = q0 + wid * 16;
  int W = *whist;

  const ushort* qptr = qb + (size_t)bh * 2048 * 64;
  const ushort* kptr = kb + (size_t)bh * 2048 * 64;
  const ushort* vptr = vt + (size_t)bh * 64 * 2048;
  const int* mrow = kmask + b * 2048;

  bf16x8 qf0, qf1;
  {
    size_t base = (size_t)(qw0 + llo) * 64 + lhi * 8;
    qf0 = *(const bf16x8*)&qptr[base];
    qf1 = *(const bf16x8*)&qptr[base + 32];
  }

  float m_[4], l_[4];
  f32x4 o[4];
#pragma unroll
  for (int j = 0; j < 4; ++j) { m_[j] = -1e30f; l_[j] = 0.f; }
#pragma unroll
  for (int nf = 0; nf < 4; ++nf) o[nf] = (f32x4){0.f, 0.f, 0.f, 0.f};

  int lo = q0 - (W - 1); if (lo < 0) lo = 0;
  int jt0 = lo & ~63;
  int nt = (q0 - jt0) / 64 + 1;                    // 64-aligned tiles up to diagonal

  bf16x8 kreg[2], vreg[2];
  int mreg[4];
  int srow = tid >> 3, sslot = tid & 7;

  auto load_tile = [&](int jt) {                   // global -> regs (prefetch)
#pragma unroll
    for (int c = 0; c < 2; ++c) {
      int row = c * 32 + srow;
      kreg[c] = *(const bf16x8*)&kptr[(size_t)(jt + row) * 64 + sslot * 8];
      vreg[c] = *(const bf16x8*)&vptr[(size_t)row * 2048 + jt + sslot * 8];
    }
#pragma unroll
    for (int kb4 = 0; kb4 < 4; ++kb4) mreg[kb4] = mrow[jt + kb4 * 16 + llo];
  };

  load_tile(jt0);
  for (int it = 0; it < nt; ++it) {
    int jt = jt0 + it * 64;
    __syncthreads();                               // prev tile's LDS reads done
    // regs -> LDS (K XOR-swizzled, V pitch-72)
#pragma unroll
    for (int c = 0; c < 2; ++c) {
      int row = c * 32 + srow;
      *(bf16x8*)&sK[row * 64 + ((sslot ^ (row & 7)) * 8)] = kreg[c];
      *(bf16x8*)&sV[row * 72 + sslot * 8] = vreg[c];
    }
    int msk[4];
#pragma unroll
    for (int kb4 = 0; kb4 < 4; ++kb4) msk[kb4] = mreg[kb4];
    if (it + 1 < nt) load_tile(jt + 64);           // prefetch hides under compute
    __syncthreads();                               // LDS tile visible

    // QK^T: 16 q x 64 keys
    f32x4 sc[4];
#pragma unroll
    for (int kb4 = 0; kb4 < 4; ++kb4) sc[kb4] = (f32x4){0.f, 0.f, 0.f, 0.f};
#pragma unroll
    for (int ks = 0; ks < 2; ++ks) {
      bf16x8 qq = ks ? qf1 : qf0;
#pragma unroll
      for (int kb4 = 0; kb4 < 4; ++kb4) {
        int r = kb4 * 16 + llo;
        bf16x8 kf = *(const bf16x8*)&sK[r * 64 + (((ks * 4 + lhi) ^ (r & 7)) * 8)];
        sc[kb4] = __builtin_amdgcn_mfma_f32_16x16x32_bf16(qq, kf, sc[kb4], 0, 0, 0);
      }
    }

    // wave-uniform fast path: tile fully inside causal+band, no padding
    int anyp = msk[0] | msk[1] | msk[2] | msk[3];
    bool fast = (jt + 63 <= qw0) && (jt > qw0 + 15 - W) && (__ballot(anyp != 0) == 0ull);

#pragma unroll
    for (int j = 0; j < 4; ++j) {
      int qi = qw0 + lhi * 4 + j;
      float s0, s1, s2, s3;
      bool ok0 = true, ok1 = true, ok2 = true, ok3 = true;
      if (fast) {
        s0 = sc[0][j]; s1 = sc[1][j]; s2 = sc[2][j]; s3 = sc[3][j];
      } else {
        int k0 = jt + llo;
        ok0 = (k0      <= qi) && (qi - k0      < W) && (msk[0] == 0);
        ok1 = (k0 + 16 <= qi) && (qi - k0 - 16 < W) && (msk[1] == 0);
        ok2 = (k0 + 32 <= qi) && (qi - k0 - 32 < W) && (msk[2] == 0);
        ok3 = (k0 + 48 <= qi) && (qi - k0 - 48 < W) && (msk[3] == 0);
        s0 = ok0 ? sc[0][j] : -1e30f;
        s1 = ok1 ? sc[1][j] : -1e30f;
        s2 = ok2 ? sc[2][j] : -1e30f;
        s3 = ok3 ? sc[3][j] : -1e30f;
      }
      float t = fmaxf(fmaxf(s0, s1), fmaxf(s2, s3));
      t = fmaxf(t, __shfl_xor(t, 1));
      t = fmaxf(t, __shfl_xor(t, 2));
      t = fmaxf(t, __shfl_xor(t, 4));
      t = fmaxf(t, __shfl_xor(t, 8));
      if (t > m_[j]) {                             // conditional rescale (exact)
        float fac = __expf(m_[j] - t);
        l_[j] *= fac;
#pragma unroll
        for (int nf = 0; nf < 4; ++nf) o[nf][j] *= fac;
        m_[j] = t;
      }
      float p0, p1, p2, p3;
      if (fast) {
        p0 = __expf(s0 - m_[j]); p1 = __expf(s1 - m_[j]);
        p2 = __expf(s2 - m_[j]); p3 = __expf(s3 - m_[j]);
      } else {                                     // masked p stays exactly 0
        p0 = ok0 ? __expf(s0 - m_[j]) : 0.f;
        p1 = ok1 ? __expf(s1 - m_[j]) : 0.f;
        p2 = ok2 ? __expf(s2 - m_[j]) : 0.f;
        p3 = ok3 ? __expf(s3 - m_[j]) : 0.f;
      }
      float ps = (p0 + p1) + (p2 + p3);
      ps += __shfl_xor(ps, 1);
      ps += __shfl_xor(ps, 2);
      ps += __shfl_xor(ps, 4);
      ps += __shfl_xor(ps, 8);
      l_[j] += ps;
      int prow = lhi * 4 + j;
      sP[wid][prow * 72 + llo]      = f2b(p0);
      sP[wid][prow * 72 + 16 + llo] = f2b(p1);
      sP[wid][prow * 72 + 32 + llo] = f2b(p2);
      sP[wid][prow * 72 + 48 + llo] = f2b(p3);
    }

    // PV: C-layout -> A-layout via wave-private LDS, then 8 MFMA
    bf16x8 pf0 = *(const bf16x8*)&sP[wid][llo * 72 + lhi * 8];
    bf16x8 pf1 = *(const bf16x8*)&sP[wid][llo * 72 + 32 + lhi * 8];
#pragma unroll
    for (int nf = 0; nf < 4; ++nf) {
      bf16x8 vf0 = *(const bf16x8*)&sV[(nf * 16 + llo) * 72 + lhi * 8];
      bf16x8 vf1 = *(const bf16x8*)&sV[(nf * 16 + llo) * 72 + 32 + lhi * 8];
      o[nf] = __builtin_amdgcn_mfma_f32_16x16x32_bf16(pf0, vf0, o[nf], 0, 0, 0);
      o[nf] = __builtin_amdgcn_mfma_f32_16x16x32_bf16(pf1, vf1, o[nf], 0, 0, 0);
    }
  }

#pragma unroll
  for (int j = 0; j < 4; ++j) {
    float inv = 1.f / l_[j];
    int qi = qw0 + lhi * 4 + j;
    size_t obase = ((size_t)b * 2048 + qi) * 1024 + (bh & 15) * 64 + llo;
#pragma unroll
    for (int nf = 0; nf < 4; ++nf)
      out[obase + nf * 16] = o[nf][j] * inv;
  }
}

// ---------------------------------------------------------------------------
extern "C" void kernel_launch(void* const* d_in, const int* in_sizes, int n_in,
                              void* d_out, int out_size, void* d_ws, size_t ws_size,
                              hipStream_t stream) {
  const float* x  = (const float*)d_in[0];
  const float* wq = (const float*)d_in[1];
  const float* bq = (const float*)d_in[2];
  const float* wk = (const float*)d_in[3];
  const float* bk = (const float*)d_in[4];
  const float* wv = (const float*)d_in[5];
  const float* bv = (const float*)d_in[6];
  const int* kmask = (const int*)d_in[7];
  const int* whist = (const int*)d_in[8];
  float* out = (float*)d_out;

  char* ws = (char*)d_ws;
  ushort* xb  = (ushort*)(ws);                       // [4096][1024] bf16   8 MB
  ushort* wt  = (ushort*)(ws + (8ull  << 20));       // [3072][1024] bf16   6 MB
  ushort* C   = (ushort*)(ws + (14ull << 20));       // [4096][3072] bf16  24 MB
  ushort* qb  = (ushort*)(ws + (38ull << 20));       // [32][2048][64]      8 MB
  ushort* kb  = (ushort*)(ws + (46ull << 20));       // [32][2048][64]      8 MB
  ushort* vt  = (ushort*)(ws + (54ull << 20));       // [32][64][2048]      8 MB
  float2* tab = (float2*)(ws + (62ull << 20));       // [2048][32] float2  .5 MB

  prep_x_kernel<<<4096, 256, 0, stream>>>(x, xb);
  prep_w_kernel<<<dim3(32, 32, 3), dim3(32, 32, 1), 0, stream>>>(wq, wk, wv, wt);
  rope_tab_kernel<<<256, 256, 0, stream>>>(tab);
  qkv_gemm_kernel<<<dim3(32, 24), 256, 0, stream>>>(xb, wt, C);
  epi_qk_kernel<<<2048, 256, 0, stream>>>(C, bq, bk, tab, qb, kb);
  epi_v_kernel<<<dim3(32, 32), 256, 0, stream>>>(C, bv, vt);
  attn_kernel<<<1024, 256, 0, stream>>>(qb, kb, vt, kmask, whist, out);
}

// Round 3
// 96.474 us; speedup vs baseline: 1.2598x; 1.2598x over previous
//
#include <hip/hip_runtime.h>
#include <hip/hip_bf16.h>
#include <stdint.h>

// ---------------------------------------------------------------------------
// MultiHeadedSelfAttention: x[2,2048,1024] -> out[2,2048,1024] (fp32)
// prep(bf16, W^T, rope table) -> fused QKV GEMM (bf16 MFMA) -> bias+RoPE
// epilogues -> banded flash attention (swapped-operand MFMA: lane-local
// softmax, KVBLK=64, reg-staged dbuf, ballot padding mask, XCD-grouped bh).
// ---------------------------------------------------------------------------

typedef __attribute__((ext_vector_type(8))) short bf16x8;
typedef __attribute__((ext_vector_type(4))) short bf16x4;
typedef __attribute__((ext_vector_type(4))) float f32x4;

#define DEV __device__ __forceinline__

DEV ushort f2b(float f) {               // fp32 -> bf16 bits, round-nearest-even
  union { float f; uint32_t u; } v; v.f = f;
  uint32_t r = v.u + 0x7FFFu + ((v.u >> 16) & 1u);
  return (ushort)(r >> 16);
}
DEV float b2f(ushort u) {
  union { uint32_t u; float f; } v; v.u = ((uint32_t)u) << 16;
  return v.f;
}

DEV void gload_lds16(const void* g, void* l) {
  __builtin_amdgcn_global_load_lds((const __attribute__((address_space(1))) void*)g,
                                   (__attribute__((address_space(3))) void*)l,
                                   16, 0, 0);
}

// ---------------------------------------------------------------------------
__global__ __launch_bounds__(256) void prep_x_kernel(const float* __restrict__ x,
                                                     ushort* __restrict__ xb) {
  int t = blockIdx.x * 256 + threadIdx.x;
  float4 v = ((const float4*)x)[t];
  bf16x4 o;
  o[0] = (short)f2b(v.x); o[1] = (short)f2b(v.y);
  o[2] = (short)f2b(v.z); o[3] = (short)f2b(v.w);
  *(bf16x4*)&xb[(size_t)t * 4] = o;
}

__global__ void prep_w_kernel(const float* __restrict__ wq, const float* __restrict__ wk,
                              const float* __restrict__ wv, ushort* __restrict__ wt) {
  __shared__ float tile[32][33];
  int which = blockIdx.z;
  const float* w = which == 0 ? wq : (which == 1 ? wk : wv);
  int n0 = blockIdx.x * 32, k0 = blockIdx.y * 32;
  tile[threadIdx.y][threadIdx.x] = w[(size_t)(k0 + threadIdx.y) * 1024 + n0 + threadIdx.x];
  __syncthreads();
  wt[((size_t)which * 1024 + n0 + threadIdx.y) * 1024 + k0 + threadIdx.x] =
      f2b(tile[threadIdx.x][threadIdx.y]);
}

__global__ __launch_bounds__(256) void rope_tab_kernel(float2* __restrict__ tab) {
  int t = blockIdx.x * 256 + threadIdx.x;          // 65536
  int i = t & 31, s = t >> 5;
  float theta = powf(10000.0f, -(float)i / 32.0f);
  float ang = (float)s * theta;
  tab[t] = make_float2(cosf(ang), sinf(ang));
}

// ---------------------------------------------------------------------------
// QKV GEMM: A = xb [4096][1024], Bt = wt [3072][1024] -> C bf16 [4096][3072]
__global__ __launch_bounds__(256) void qkv_gemm_kernel(const ushort* __restrict__ A,
                                                       const ushort* __restrict__ Bt,
                                                       ushort* __restrict__ C) {
  const int K = 1024, N = 3072;
  __shared__ alignas(16) ushort sA[2][128 * 32];
  __shared__ alignas(16) ushort sB[2][128 * 32];
  int tid = threadIdx.x;
  int bm = blockIdx.x, bn = blockIdx.y;
  int lane = tid & 63, wid = tid >> 6;
  int lhi = lane >> 4, llo = lane & 15;
  int wr = wid >> 1, wc = wid & 1;

  const ushort* Abase = A + (size_t)bm * 128 * K;
  const ushort* Bbase = Bt + (size_t)bn * 128 * K;

  f32x4 acc[4][4];
#pragma unroll
  for (int i = 0; i < 4; ++i)
#pragma unroll
    for (int j = 0; j < 4; ++j) acc[i][j] = (f32x4){0.f, 0.f, 0.f, 0.f};

  auto stage = [&](int kt, int buf) {
    int k0 = kt * 32;
#pragma unroll
    for (int c = 0; c < 2; ++c) {
      int idx = c * 256 + tid;
      int row = idx >> 2, col = (idx & 3) * 8;
      gload_lds16(Abase + (size_t)row * K + k0 + col, &sA[buf][(idx & ~63) * 8]);
      gload_lds16(Bbase + (size_t)row * K + k0 + col, &sB[buf][(idx & ~63) * 8]);
    }
  };

  stage(0, 0);
  for (int kt = 0; kt < 32; ++kt) {
    __syncthreads();
    if (kt + 1 < 32) stage(kt + 1, (kt + 1) & 1);
    int buf = kt & 1;
    bf16x8 af[4], bfr[4];
#pragma unroll
    for (int mf = 0; mf < 4; ++mf)
      af[mf] = *(const bf16x8*)&sA[buf][(wr * 64 + mf * 16 + llo) * 32 + lhi * 8];
#pragma unroll
    for (int nf = 0; nf < 4; ++nf)
      bfr[nf] = *(const bf16x8*)&sB[buf][(wc * 64 + nf * 16 + llo) * 32 + lhi * 8];
#pragma unroll
    for (int mf = 0; mf < 4; ++mf)
#pragma unroll
      for (int nf = 0; nf < 4; ++nf)
        acc[mf][nf] = __builtin_amdgcn_mfma_f32_16x16x32_bf16(af[mf], bfr[nf], acc[mf][nf], 0, 0, 0);
  }
#pragma unroll
  for (int mf = 0; mf < 4; ++mf)
#pragma unroll
    for (int nf = 0; nf < 4; ++nf)
#pragma unroll
      for (int j = 0; j < 4; ++j) {
        int row = bm * 128 + wr * 64 + mf * 16 + lhi * 4 + j;
        int col = bn * 128 + wc * 64 + nf * 16 + llo;
        C[(size_t)row * N + col] = f2b(acc[mf][nf][j]);
      }
}

// ---------------------------------------------------------------------------
// epilogue: bias + RoPE, vectorized 8 elems/thread. q pre-scaled by 0.125.
__global__ __launch_bounds__(256) void epi_qk_kernel(const ushort* __restrict__ C,
    const float* __restrict__ bq, const float* __restrict__ bk,
    const float2* __restrict__ tab,
    ushort* __restrict__ qb, ushort* __restrict__ kb) {
  int t = blockIdx.x * 256 + threadIdx.x;          // 4096*128
  int m = t >> 7, pp = (t & 127) << 3;
  int s = m & 2047;
  int h = pp >> 6, i0 = (pp & 63) >> 1;
  size_t crow = (size_t)m * 3072;
  bf16x8 qv = *(const bf16x8*)&C[crow + pp];
  bf16x8 kv = *(const bf16x8*)&C[crow + 1024 + pp];
  float4 bq0 = *(const float4*)&bq[pp], bq1 = *(const float4*)&bq[pp + 4];
  float4 bk0 = *(const float4*)&bk[pp], bk1 = *(const float4*)&bk[pp + 4];
  float4 cs01 = *(const float4*)&tab[s * 32 + i0];
  float4 cs23 = *(const float4*)&tab[s * 32 + i0 + 2];
  float cth[4] = {cs01.x, cs01.z, cs23.x, cs23.z};
  float sth[4] = {cs01.y, cs01.w, cs23.y, cs23.w};
  float bqa[8] = {bq0.x, bq0.y, bq0.z, bq0.w, bq1.x, bq1.y, bq1.z, bq1.w};
  float bka[8] = {bk0.x, bk0.y, bk0.z, bk0.w, bk1.x, bk1.y, bk1.z, bk1.w};
  bf16x8 qo, ko;
#pragma unroll
  for (int e = 0; e < 4; ++e) {
    float t0 = b2f((ushort)qv[2 * e])     + bqa[2 * e];
    float t1 = b2f((ushort)qv[2 * e + 1]) + bqa[2 * e + 1];
    qo[2 * e]     = (short)f2b((t0 * cth[e] - t1 * sth[e]) * 0.125f);
    qo[2 * e + 1] = (short)f2b((t1 * cth[e] + t0 * sth[e]) * 0.125f);
    float u0 = b2f((ushort)kv[2 * e])     + bka[2 * e];
    float u1 = b2f((ushort)kv[2 * e + 1]) + bka[2 * e + 1];
    ko[2 * e]     = (short)f2b(u0 * cth[e] - u1 * sth[e]);
    ko[2 * e + 1] = (short)f2b(u1 * cth[e] + u0 * sth[e]);
  }
  int bh = (m >> 11) * 16 + h;
  size_t ooff = ((size_t)bh * 2048 + s) * 64 + (pp & 63);
  *(bf16x8*)&qb[ooff] = qo;
  *(bf16x8*)&kb[ooff] = ko;
}

// epilogue: bias + transpose for v -> vt [32][64][2048] bf16
__global__ __launch_bounds__(256) void epi_v_kernel(const ushort* __restrict__ C,
    const float* __restrict__ bv, ushort* __restrict__ vt) {
  __shared__ float lv[64][65];
  int bh = blockIdx.y; int h = bh & 15;
  int s0 = blockIdx.x * 64;
  int tid = threadIdx.x;
  size_t mbase = (size_t)(bh >> 4) * 2048 + s0;
#pragma unroll
  for (int ph = 0; ph < 2; ++ph) {
    int idx = ph * 256 + tid;
    int row = idx >> 3, col = (idx & 7) * 8;
    bf16x8 v = *(const bf16x8*)&C[(mbase + row) * 3072 + 2048 + h * 64 + col];
#pragma unroll
    for (int e = 0; e < 8; ++e) lv[row][col + e] = b2f((ushort)v[e]);
  }
  __syncthreads();
#pragma unroll
  for (int ph = 0; ph < 2; ++ph) {
    int idx = ph * 256 + tid;
    int hd = idx >> 3, s8 = (idx & 7) * 8;
    float bias = bv[h * 64 + hd];
    bf16x8 o;
#pragma unroll
    for (int e = 0; e < 8; ++e) o[e] = (short)f2b(lv[s8 + e][hd] + bias);
    *(bf16x8*)&vt[((size_t)bh * 64 + hd) * 2048 + s0 + s8] = o;
  }
}

// ---------------------------------------------------------------------------
// banded flash attention, swapped-operand form.
// S^T = mfma(K_frag, Q_frag): lane holds 16 scores of q = qw0 + (lane&15);
// softmax is lane-local (+2 shuffles across the 4 lhi groups).
// O^T = mfma(V^T_frag, P_frag): rescale / divide lane-local; P routed through
// wave-private LDS (8 dword writes, one b128 read pair).
__global__ __launch_bounds__(256) void attn_kernel(
    const ushort* __restrict__ qb, const ushort* __restrict__ kb,
    const ushort* __restrict__ vt, const int* __restrict__ kmask,
    const int* __restrict__ whist, float* __restrict__ out) {
  __shared__ alignas(16) ushort sK[64 * 64];       // [64 keys][64 hd], XOR-swizzled
  __shared__ alignas(16) ushort sV[64 * 72];       // [64 d][64 keys], pitch 72
  __shared__ alignas(16) uint   sPd[4][16 * 36];   // per-wave P [16 q][64 k] bf16, pitch 36 dw

  int tid = threadIdx.x;
  int lane = tid & 63, wid = tid >> 6;
  int lhi = lane >> 4, llo = lane & 15;

  int id = blockIdx.x;
  int xcd = id & 7, sub = id >> 3;                 // group same-bh blocks per XCD (T1)
  int bh = xcd * 4 + (sub >> 5);
  int qtile = sub & 31;
  int b = bh >> 4;
  int q0 = qtile * 64;
  int qw0 = q0 + wid * 16;
  int W = *whist;

  const ushort* qptr = qb + (size_t)bh * 2048 * 64;
  const ushort* kptr = kb + (size_t)bh * 2048 * 64;
  const ushort* vptr = vt + (size_t)bh * 64 * 2048;
  const int* mrow = kmask + b * 2048;

  bf16x8 qf0, qf1;                                 // Q frag, q = llo, hd halves
  {
    size_t base = (size_t)(qw0 + llo) * 64 + lhi * 8;
    qf0 = *(const bf16x8*)&qptr[base];
    qf1 = *(const bf16x8*)&qptr[base + 32];
  }

  float m_ = -1e30f, l_ = 0.f;                     // lane-local: q = qw0 + llo
  f32x4 o[4];                                      // O^T: d = nf*16 + lhi*4 + j, q = llo
#pragma unroll
  for (int nf = 0; nf < 4; ++nf) o[nf] = (f32x4){0.f, 0.f, 0.f, 0.f};

  int lo = q0 - (W - 1); if (lo < 0) lo = 0;
  int jt0 = lo & ~63;
  int nt = (q0 - jt0) / 64 + 1;

  bf16x8 kreg[2], vreg[2];
  int mreg;
  int srow = tid >> 3, sslot = tid & 7;

  auto load_tile = [&](int jt) {                   // global -> regs (prefetch)
#pragma unroll
    for (int c = 0; c < 2; ++c) {
      int row = c * 32 + srow;
      kreg[c] = *(const bf16x8*)&kptr[(size_t)(jt + row) * 64 + sslot * 8];
      vreg[c] = *(const bf16x8*)&vptr[(size_t)row * 2048 + jt + sslot * 8];
    }
    mreg = mrow[jt + lane];
  };

  load_tile(jt0);
  for (int it = 0; it < nt; ++it) {
    int jt = jt0 + it * 64;
    __syncthreads();                               // prev tile's LDS reads done
#pragma unroll
    for (int c = 0; c < 2; ++c) {
      int row = c * 32 + srow;
      *(bf16x8*)&sK[row * 64 + ((sslot ^ (row & 7)) * 8)] = kreg[c];
      *(bf16x8*)&sV[row * 72 + sslot * 8] = vreg[c];
    }
    unsigned long long pm = __ballot(mreg != 0);   // padded-key bitmask (wave-uniform)
    if (it + 1 < nt) load_tile(jt + 64);           // prefetch hides under compute
    __syncthreads();                               // LDS tile visible

    // S^T = K Q^T : sc[kb4] row = key offset (lhi*4+j), col = q (llo)
    f32x4 sc[4];
#pragma unroll
    for (int kb4 = 0; kb4 < 4; ++kb4) sc[kb4] = (f32x4){0.f, 0.f, 0.f, 0.f};
    __builtin_amdgcn_s_setprio(1);
#pragma unroll
    for (int ks = 0; ks < 2; ++ks) {
      bf16x8 qq = ks ? qf1 : qf0;
#pragma unroll
      for (int kb4 = 0; kb4 < 4; ++kb4) {
        int r = kb4 * 16 + llo;
        bf16x8 kf = *(const bf16x8*)&sK[r * 64 + (((ks * 4 + lhi) ^ (r & 7)) * 8)];
        sc[kb4] = __builtin_amdgcn_mfma_f32_16x16x32_bf16(kf, qq, sc[kb4], 0, 0, 0);
      }
    }
    __builtin_amdgcn_s_setprio(0);

    bool fast = (jt + 63 <= qw0) && (jt >= qw0 + 16 - W) && (pm == 0ull);
    float s[16];
    bool ok[16];
    if (fast) {
#pragma unroll
      for (int kb4 = 0; kb4 < 4; ++kb4)
#pragma unroll
        for (int j = 0; j < 4; ++j) s[kb4 * 4 + j] = sc[kb4][j];
    } else {
      int qi = qw0 + llo;
#pragma unroll
      for (int kb4 = 0; kb4 < 4; ++kb4) {
        uint nib = (uint)(pm >> (kb4 * 16 + lhi * 4)) & 0xFu;
#pragma unroll
        for (int j = 0; j < 4; ++j) {
          int key = jt + kb4 * 16 + lhi * 4 + j;
          bool k_ok = (key <= qi) && (qi - key < W) && !((nib >> j) & 1u);
          ok[kb4 * 4 + j] = k_ok;
          s[kb4 * 4 + j] = k_ok ? sc[kb4][j] : -1e30f;
        }
      }
    }

    // lane-local max over 16 + 2 shuffles across lhi groups
    float t01 = fmaxf(s[0], s[1]),  t23 = fmaxf(s[2], s[3]);
    float t45 = fmaxf(s[4], s[5]),  t67 = fmaxf(s[6], s[7]);
    float t89 = fmaxf(s[8], s[9]),  tab_ = fmaxf(s[10], s[11]);
    float tcd = fmaxf(s[12], s[13]), tef = fmaxf(s[14], s[15]);
    float t = fmaxf(fmaxf(fmaxf(t01, t23), fmaxf(t45, t67)),
                    fmaxf(fmaxf(t89, tab_), fmaxf(tcd, tef)));
    t = fmaxf(t, __shfl_xor(t, 16));
    t = fmaxf(t, __shfl_xor(t, 32));

    if (t > m_ + 8.f) {                            // defer-max (T13, THR=8)
      float fac = __expf(m_ - t);
      l_ *= fac;
#pragma unroll
      for (int nf = 0; nf < 4; ++nf) o[nf] *= fac;
      m_ = t;
    }

    float p[16];
    if (fast) {
#pragma unroll
      for (int i = 0; i < 16; ++i) p[i] = __expf(s[i] - m_);
    } else {                                       // masked p exactly 0
#pragma unroll
      for (int i = 0; i < 16; ++i) p[i] = ok[i] ? __expf(s[i] - m_) : 0.f;
    }
    float ps = ((p[0] + p[1]) + (p[2] + p[3])) + ((p[4] + p[5]) + (p[6] + p[7]))
             + ((p[8] + p[9]) + (p[10] + p[11])) + ((p[12] + p[13]) + (p[14] + p[15]));
    ps += __shfl_xor(ps, 16);
    ps += __shfl_xor(ps, 32);
    l_ += ps;

    // P (fp32, lane q=llo, keys kb4*16+lhi*4+j) -> wave-private LDS as bf16
#pragma unroll
    for (int kb4 = 0; kb4 < 4; ++kb4) {
      uint d0 = (uint)f2b(p[kb4 * 4 + 0]) | ((uint)f2b(p[kb4 * 4 + 1]) << 16);
      uint d1 = (uint)f2b(p[kb4 * 4 + 2]) | ((uint)f2b(p[kb4 * 4 + 3]) << 16);
      sPd[wid][llo * 36 + kb4 * 8 + lhi * 2]     = d0;
      sPd[wid][llo * 36 + kb4 * 8 + lhi * 2 + 1] = d1;
    }
    bf16x8 pf0 = *(const bf16x8*)&sPd[wid][llo * 36 + lhi * 4];        // keys 0..31
    bf16x8 pf1 = *(const bf16x8*)&sPd[wid][llo * 36 + 16 + lhi * 4];   // keys 32..63

    // O^T += V^T P^T : o row = d offset, col = q
    __builtin_amdgcn_s_setprio(1);
#pragma unroll
    for (int nf = 0; nf < 4; ++nf) {
      bf16x8 vf0 = *(const bf16x8*)&sV[(nf * 16 + llo) * 72 + lhi * 8];
      bf16x8 vf1 = *(const bf16x8*)&sV[(nf * 16 + llo) * 72 + 32 + lhi * 8];
      o[nf] = __builtin_amdgcn_mfma_f32_16x16x32_bf16(vf0, pf0, o[nf], 0, 0, 0);
      o[nf] = __builtin_amdgcn_mfma_f32_16x16x32_bf16(vf1, pf1, o[nf], 0, 0, 0);
    }
    __builtin_amdgcn_s_setprio(0);
  }

  float inv = 1.f / l_;
  int qi = qw0 + llo;
  size_t obase = ((size_t)b * 2048 + qi) * 1024 + (bh & 15) * 64 + lhi * 4;
#pragma unroll
  for (int nf = 0; nf < 4; ++nf) {
    float4 st = make_float4(o[nf][0] * inv, o[nf][1] * inv, o[nf][2] * inv, o[nf][3] * inv);
    *(float4*)&out[obase + nf * 16] = st;
  }
}

// ---------------------------------------------------------------------------
extern "C" void kernel_launch(void* const* d_in, const int* in_sizes, int n_in,
                              void* d_out, int out_size, void* d_ws, size_t ws_size,
                              hipStream_t stream) {
  const float* x  = (const float*)d_in[0];
  const float* wq = (const float*)d_in[1];
  const float* bq = (const float*)d_in[2];
  const float* wk = (const float*)d_in[3];
  const float* bk = (const float*)d_in[4];
  const float* wv = (const float*)d_in[5];
  const float* bv = (const float*)d_in[6];
  const int* kmask = (const int*)d_in[7];
  const int* whist = (const int*)d_in[8];
  float* out = (float*)d_out;

  char* ws = (char*)d_ws;
  ushort* xb  = (ushort*)(ws);                       // [4096][1024] bf16   8 MB
  ushort* wt  = (ushort*)(ws + (8ull  << 20));       // [3072][1024] bf16   6 MB
  ushort* C   = (ushort*)(ws + (14ull << 20));       // [4096][3072] bf16  24 MB
  ushort* qb  = (ushort*)(ws + (38ull << 20));       // [32][2048][64]      8 MB
  ushort* kb  = (ushort*)(ws + (46ull << 20));       // [32][2048][64]      8 MB
  ushort* vt  = (ushort*)(ws + (54ull << 20));       // [32][64][2048]      8 MB
  float2* tab = (float2*)(ws + (62ull << 20));       // [2048][32] float2  .5 MB

  prep_x_kernel<<<4096, 256, 0, stream>>>(x, xb);
  prep_w_kernel<<<dim3(32, 32, 3), dim3(32, 32, 1), 0, stream>>>(wq, wk, wv, wt);
  rope_tab_kernel<<<256, 256, 0, stream>>>(tab);
  qkv_gemm_kernel<<<dim3(32, 24), 256, 0, stream>>>(xb, wt, C);
  epi_qk_kernel<<<2048, 256, 0, stream>>>(C, bq, bk, tab, qb, kb);
  epi_v_kernel<<<dim3(32, 32), 256, 0, stream>>>(C, bv, vt);
  attn_kernel<<<1024, 256, 0, stream>>>(qb, kb, vt, kmask, whist, out);
}

// Round 4
// 92.586 us; speedup vs baseline: 1.3127x; 1.0420x over previous
//
#include <hip/hip_runtime.h>
#include <hip/hip_bf16.h>
#include <stdint.h>

// ---------------------------------------------------------------------------
// MultiHeadedSelfAttention: x[2,2048,1024] -> out[2,2048,1024] (fp32)
// prep(bf16, W^T, rope table) -> fused QKV GEMM (256x192 tile, counted-vmcnt
// triple-buffer pipeline, bf16 MFMA) -> bias+RoPE epilogues -> banded flash
// attention (swapped-operand MFMA, lane-local softmax).
// ---------------------------------------------------------------------------

typedef __attribute__((ext_vector_type(8))) short bf16x8;
typedef __attribute__((ext_vector_type(4))) short bf16x4;
typedef __attribute__((ext_vector_type(4))) float f32x4;

#define DEV __device__ __forceinline__

DEV ushort f2b(float f) {               // fp32 -> bf16 bits, round-nearest-even
  union { float f; uint32_t u; } v; v.f = f;
  uint32_t r = v.u + 0x7FFFu + ((v.u >> 16) & 1u);
  return (ushort)(r >> 16);
}
DEV float b2f(ushort u) {
  union { uint32_t u; float f; } v; v.u = ((uint32_t)u) << 16;
  return v.f;
}

DEV void gload_lds16(const void* g, void* l) {
  __builtin_amdgcn_global_load_lds((const __attribute__((address_space(1))) void*)g,
                                   (__attribute__((address_space(3))) void*)l,
                                   16, 0, 0);
}

// ---------------------------------------------------------------------------
__global__ __launch_bounds__(256) void prep_x_kernel(const float* __restrict__ x,
                                                     ushort* __restrict__ xb) {
  int t = blockIdx.x * 256 + threadIdx.x;
  float4 v = ((const float4*)x)[t];
  bf16x4 o;
  o[0] = (short)f2b(v.x); o[1] = (short)f2b(v.y);
  o[2] = (short)f2b(v.z); o[3] = (short)f2b(v.w);
  *(bf16x4*)&xb[(size_t)t * 4] = o;
}

__global__ void prep_w_kernel(const float* __restrict__ wq, const float* __restrict__ wk,
                              const float* __restrict__ wv, ushort* __restrict__ wt) {
  __shared__ float tile[32][33];
  int which = blockIdx.z;
  const float* w = which == 0 ? wq : (which == 1 ? wk : wv);
  int n0 = blockIdx.x * 32, k0 = blockIdx.y * 32;
  tile[threadIdx.y][threadIdx.x] = w[(size_t)(k0 + threadIdx.y) * 1024 + n0 + threadIdx.x];
  __syncthreads();
  wt[((size_t)which * 1024 + n0 + threadIdx.y) * 1024 + k0 + threadIdx.x] =
      f2b(tile[threadIdx.x][threadIdx.y]);
}

__global__ __launch_bounds__(256) void rope_tab_kernel(float2* __restrict__ tab) {
  int t = blockIdx.x * 256 + threadIdx.x;          // 65536
  int i = t & 31, s = t >> 5;
  float theta = powf(10000.0f, -(float)i / 32.0f);
  float ang = (float)s * theta;
  tab[t] = make_float2(cosf(ang), sinf(ang));
}

// ---------------------------------------------------------------------------
// QKV GEMM: A = xb [4096][1024], Bt = wt [3072][1024] -> C bf16 [4096][3072]
// 256x192 tile, BK=32, 8 waves (2Mx4N, per-wave 128x48), triple-buffered LDS,
// raw s_barrier + counted vmcnt (loads stay in flight across barriers).
__global__ __launch_bounds__(512, 2) void qkv_gemm_kernel(const ushort* __restrict__ A,
                                                          const ushort* __restrict__ Bt,
                                                          ushort* __restrict__ C) {
  const int K = 1024, N = 3072;
  __shared__ alignas(16) ushort sS[3][2][256 * 32];   // [buf][A/B][256 rows][32 k]

  int tid = threadIdx.x;
  int lane = tid & 63;
  int lhi = lane >> 4, llo = lane & 15;
  int wid = tid >> 6;
  int wr = wid >> 2, wc = wid & 3;                    // 2M x 4N waves

  int id = blockIdx.x;
  int wg = (id & 7) * 32 + (id >> 3);                 // XCD-grouped (256 = 8 x 32)
  int bm = wg >> 4, bn = wg & 15;                     // 16 x 16 tiles

  const ushort* Abase = A + (size_t)bm * 256 * K;
  const ushort* Bbase = Bt + (size_t)bn * 192 * K;

  f32x4 acc[8][3];
#pragma unroll
  for (int mf = 0; mf < 8; ++mf)
#pragma unroll
    for (int nf = 0; nf < 3; ++nf) acc[mf][nf] = (f32x4){0.f, 0.f, 0.f, 0.f};

  auto stage = [&](int kt, int bb) {                  // 4 gload_lds per thread
    int k0 = kt * 32;
#pragma unroll
    for (int c = 0; c < 2; ++c) {
      int idx = c * 512 + tid;                        // [0,1024): A rows 0..255
      int rowA = idx >> 2, col = (idx & 3) * 8;
      gload_lds16(Abase + (size_t)rowA * K + k0 + col, &sS[bb][0][idx * 8]);
      int rowB = rowA < 192 ? rowA : 191;             // clamp (rows 192..255 unused)
      gload_lds16(Bbase + (size_t)rowB * K + k0 + col, &sS[bb][1][idx * 8]);
    }
  };

  stage(0, 0); stage(1, 1); stage(2, 2);              // 12 loads in flight

  int bb = 0;
  for (int kt = 0; kt < 32; ++kt) {
    // wait for tile kt (oldest 4 loads) without draining tiles kt+1, kt+2
    if (kt <= 29)      asm volatile("s_waitcnt vmcnt(8)" ::: "memory");
    else if (kt == 30) asm volatile("s_waitcnt vmcnt(4)" ::: "memory");
    else               asm volatile("s_waitcnt vmcnt(0)" ::: "memory");
    __builtin_amdgcn_sched_barrier(0);
    __builtin_amdgcn_s_barrier();                     // all waves' portions landed
    __builtin_amdgcn_sched_barrier(0);

    const ushort* pA = sS[bb][0];
    const ushort* pB = sS[bb][1];
    bf16x8 af[8], bfr[3];
#pragma unroll
    for (int mf = 0; mf < 8; ++mf)
      af[mf] = *(const bf16x8*)&pA[(wr * 128 + mf * 16 + llo) * 32 + lhi * 8];
#pragma unroll
    for (int nf = 0; nf < 3; ++nf)
      bfr[nf] = *(const bf16x8*)&pB[(wc * 48 + nf * 16 + llo) * 32 + lhi * 8];
    __builtin_amdgcn_s_setprio(1);
#pragma unroll
    for (int mf = 0; mf < 8; ++mf)
#pragma unroll
      for (int nf = 0; nf < 3; ++nf)
        acc[mf][nf] = __builtin_amdgcn_mfma_f32_16x16x32_bf16(af[mf], bfr[nf], acc[mf][nf], 0, 0, 0);
    __builtin_amdgcn_s_setprio(0);

    __builtin_amdgcn_sched_barrier(0);
    __builtin_amdgcn_s_barrier();                     // all reads of buf bb done
    __builtin_amdgcn_sched_barrier(0);
    if (kt + 3 < 32) stage(kt + 3, bb);               // refill freed buffer
    bb = (bb == 2) ? 0 : bb + 1;
  }

#pragma unroll
  for (int mf = 0; mf < 8; ++mf)
#pragma unroll
    for (int nf = 0; nf < 3; ++nf)
#pragma unroll
      for (int j = 0; j < 4; ++j) {
        int row = bm * 256 + wr * 128 + mf * 16 + lhi * 4 + j;
        int col = bn * 192 + wc * 48 + nf * 16 + llo;
        C[(size_t)row * N + col] = f2b(acc[mf][nf][j]);
      }
}

// ---------------------------------------------------------------------------
// epilogue: bias + RoPE, vectorized 8 elems/thread. q pre-scaled by 0.125.
__global__ __launch_bounds__(256) void epi_qk_kernel(const ushort* __restrict__ C,
    const float* __restrict__ bq, const float* __restrict__ bk,
    const float2* __restrict__ tab,
    ushort* __restrict__ qb, ushort* __restrict__ kb) {
  int t = blockIdx.x * 256 + threadIdx.x;          // 4096*128
  int m = t >> 7, pp = (t & 127) << 3;
  int s = m & 2047;
  int h = pp >> 6, i0 = (pp & 63) >> 1;
  size_t crow = (size_t)m * 3072;
  bf16x8 qv = *(const bf16x8*)&C[crow + pp];
  bf16x8 kv = *(const bf16x8*)&C[crow + 1024 + pp];
  float4 bq0 = *(const float4*)&bq[pp], bq1 = *(const float4*)&bq[pp + 4];
  float4 bk0 = *(const float4*)&bk[pp], bk1 = *(const float4*)&bk[pp + 4];
  float4 cs01 = *(const float4*)&tab[s * 32 + i0];
  float4 cs23 = *(const float4*)&tab[s * 32 + i0 + 2];
  float cth[4] = {cs01.x, cs01.z, cs23.x, cs23.z};
  float sth[4] = {cs01.y, cs01.w, cs23.y, cs23.w};
  float bqa[8] = {bq0.x, bq0.y, bq0.z, bq0.w, bq1.x, bq1.y, bq1.z, bq1.w};
  float bka[8] = {bk0.x, bk0.y, bk0.z, bk0.w, bk1.x, bk1.y, bk1.z, bk1.w};
  bf16x8 qo, ko;
#pragma unroll
  for (int e = 0; e < 4; ++e) {
    float t0 = b2f((ushort)qv[2 * e])     + bqa[2 * e];
    float t1 = b2f((ushort)qv[2 * e + 1]) + bqa[2 * e + 1];
    qo[2 * e]     = (short)f2b((t0 * cth[e] - t1 * sth[e]) * 0.125f);
    qo[2 * e + 1] = (short)f2b((t1 * cth[e] + t0 * sth[e]) * 0.125f);
    float u0 = b2f((ushort)kv[2 * e])     + bka[2 * e];
    float u1 = b2f((ushort)kv[2 * e + 1]) + bka[2 * e + 1];
    ko[2 * e]     = (short)f2b(u0 * cth[e] - u1 * sth[e]);
    ko[2 * e + 1] = (short)f2b(u1 * cth[e] + u0 * sth[e]);
  }
  int bh = (m >> 11) * 16 + h;
  size_t ooff = ((size_t)bh * 2048 + s) * 64 + (pp & 63);
  *(bf16x8*)&qb[ooff] = qo;
  *(bf16x8*)&kb[ooff] = ko;
}

// epilogue: bias + transpose for v -> vt [32][64][2048] bf16
__global__ __launch_bounds__(256) void epi_v_kernel(const ushort* __restrict__ C,
    const float* __restrict__ bv, ushort* __restrict__ vt) {
  __shared__ float lv[64][65];
  int bh = blockIdx.y; int h = bh & 15;
  int s0 = blockIdx.x * 64;
  int tid = threadIdx.x;
  size_t mbase = (size_t)(bh >> 4) * 2048 + s0;
#pragma unroll
  for (int ph = 0; ph < 2; ++ph) {
    int idx = ph * 256 + tid;
    int row = idx >> 3, col = (idx & 7) * 8;
    bf16x8 v = *(const bf16x8*)&C[(mbase + row) * 3072 + 2048 + h * 64 + col];
#pragma unroll
    for (int e = 0; e < 8; ++e) lv[row][col + e] = b2f((ushort)v[e]);
  }
  __syncthreads();
#pragma unroll
  for (int ph = 0; ph < 2; ++ph) {
    int idx = ph * 256 + tid;
    int hd = idx >> 3, s8 = (idx & 7) * 8;
    float bias = bv[h * 64 + hd];
    bf16x8 o;
#pragma unroll
    for (int e = 0; e < 8; ++e) o[e] = (short)f2b(lv[s8 + e][hd] + bias);
    *(bf16x8*)&vt[((size_t)bh * 64 + hd) * 2048 + s0 + s8] = o;
  }
}

// ---------------------------------------------------------------------------
// banded flash attention, swapped-operand form.
__global__ __launch_bounds__(256) void attn_kernel(
    const ushort* __restrict__ qb, const ushort* __restrict__ kb,
    const ushort* __restrict__ vt, const int* __restrict__ kmask,
    const int* __restrict__ whist, float* __restrict__ out) {
  __shared__ alignas(16) ushort sK[64 * 64];       // [64 keys][64 hd], XOR-swizzled
  __shared__ alignas(16) ushort sV[64 * 72];       // [64 d][64 keys], pitch 72
  __shared__ alignas(16) uint   sPd[4][16 * 36];   // per-wave P [16 q][64 k] bf16, pitch 36 dw

  int tid = threadIdx.x;
  int lane = tid & 63, wid = tid >> 6;
  int lhi = lane >> 4, llo = lane & 15;

  int id = blockIdx.x;
  int xcd = id & 7, sub = id >> 3;                 // group same-bh blocks per XCD (T1)
  int bh = xcd * 4 + (sub >> 5);
  int qtile = sub & 31;
  int b = bh >> 4;
  int q0 = qtile * 64;
  int qw0 = q0 + wid * 16;
  int W = *whist;

  const ushort* qptr = qb + (size_t)bh * 2048 * 64;
  const ushort* kptr = kb + (size_t)bh * 2048 * 64;
  const ushort* vptr = vt + (size_t)bh * 64 * 2048;
  const int* mrow = kmask + b * 2048;

  bf16x8 qf0, qf1;                                 // Q frag, q = llo, hd halves
  {
    size_t base = (size_t)(qw0 + llo) * 64 + lhi * 8;
    qf0 = *(const bf16x8*)&qptr[base];
    qf1 = *(const bf16x8*)&qptr[base + 32];
  }

  float m_ = -1e30f, l_ = 0.f;                     // lane-local: q = qw0 + llo
  f32x4 o[4];                                      // O^T: d = nf*16 + lhi*4 + j, q = llo
#pragma unroll
  for (int nf = 0; nf < 4; ++nf) o[nf] = (f32x4){0.f, 0.f, 0.f, 0.f};

  int lo = q0 - (W - 1); if (lo < 0) lo = 0;
  int jt0 = lo & ~63;
  int nt = (q0 - jt0) / 64 + 1;

  bf16x8 kreg[2], vreg[2];
  int mreg;
  int srow = tid >> 3, sslot = tid & 7;

  auto load_tile = [&](int jt) {                   // global -> regs (prefetch)
#pragma unroll
    for (int c = 0; c < 2; ++c) {
      int row = c * 32 + srow;
      kreg[c] = *(const bf16x8*)&kptr[(size_t)(jt + row) * 64 + sslot * 8];
      vreg[c] = *(const bf16x8*)&vptr[(size_t)row * 2048 + jt + sslot * 8];
    }
    mreg = mrow[jt + lane];
  };

  load_tile(jt0);
  for (int it = 0; it < nt; ++it) {
    int jt = jt0 + it * 64;
    __syncthreads();                               // prev tile's LDS reads done
#pragma unroll
    for (int c = 0; c < 2; ++c) {
      int row = c * 32 + srow;
      *(bf16x8*)&sK[row * 64 + ((sslot ^ (row & 7)) * 8)] = kreg[c];
      *(bf16x8*)&sV[row * 72 + sslot * 8] = vreg[c];
    }
    unsigned long long pm = __ballot(mreg != 0);   // padded-key bitmask (wave-uniform)
    if (it + 1 < nt) load_tile(jt + 64);           // prefetch hides under compute
    __syncthreads();                               // LDS tile visible

    // S^T = K Q^T : sc[kb4] row = key offset (lhi*4+j), col = q (llo)
    f32x4 sc[4];
#pragma unroll
    for (int kb4 = 0; kb4 < 4; ++kb4) sc[kb4] = (f32x4){0.f, 0.f, 0.f, 0.f};
    __builtin_amdgcn_s_setprio(1);
#pragma unroll
    for (int ks = 0; ks < 2; ++ks) {
      bf16x8 qq = ks ? qf1 : qf0;
#pragma unroll
      for (int kb4 = 0; kb4 < 4; ++kb4) {
        int r = kb4 * 16 + llo;
        bf16x8 kf = *(const bf16x8*)&sK[r * 64 + (((ks * 4 + lhi) ^ (r & 7)) * 8)];
        sc[kb4] = __builtin_amdgcn_mfma_f32_16x16x32_bf16(kf, qq, sc[kb4], 0, 0, 0);
      }
    }
    __builtin_amdgcn_s_setprio(0);

    bool fast = (jt + 63 <= qw0) && (jt >= qw0 + 16 - W) && (pm == 0ull);
    float s[16];
    bool ok[16];
    if (fast) {
#pragma unroll
      for (int kb4 = 0; kb4 < 4; ++kb4)
#pragma unroll
        for (int j = 0; j < 4; ++j) s[kb4 * 4 + j] = sc[kb4][j];
    } else {
      int qi = qw0 + llo;
#pragma unroll
      for (int kb4 = 0; kb4 < 4; ++kb4) {
        uint nib = (uint)(pm >> (kb4 * 16 + lhi * 4)) & 0xFu;
#pragma unroll
        for (int j = 0; j < 4; ++j) {
          int key = jt + kb4 * 16 + lhi * 4 + j;
          bool k_ok = (key <= qi) && (qi - key < W) && !((nib >> j) & 1u);
          ok[kb4 * 4 + j] = k_ok;
          s[kb4 * 4 + j] = k_ok ? sc[kb4][j] : -1e30f;
        }
      }
    }

    // lane-local max over 16 + 2 shuffles across lhi groups
    float t01 = fmaxf(s[0], s[1]),  t23 = fmaxf(s[2], s[3]);
    float t45 = fmaxf(s[4], s[5]),  t67 = fmaxf(s[6], s[7]);
    float t89 = fmaxf(s[8], s[9]),  tab_ = fmaxf(s[10], s[11]);
    float tcd = fmaxf(s[12], s[13]), tef = fmaxf(s[14], s[15]);
    float t = fmaxf(fmaxf(fmaxf(t01, t23), fmaxf(t45, t67)),
                    fmaxf(fmaxf(t89, tab_), fmaxf(tcd, tef)));
    t = fmaxf(t, __shfl_xor(t, 16));
    t = fmaxf(t, __shfl_xor(t, 32));

    if (t > m_ + 8.f) {                            // defer-max (T13, THR=8)
      float fac = __expf(m_ - t);
      l_ *= fac;
#pragma unroll
      for (int nf = 0; nf < 4; ++nf) o[nf] *= fac;
      m_ = t;
    }

    float p[16];
    if (fast) {
#pragma unroll
      for (int i = 0; i < 16; ++i) p[i] = __expf(s[i] - m_);
    } else {                                       // masked p exactly 0
#pragma unroll
      for (int i = 0; i < 16; ++i) p[i] = ok[i] ? __expf(s[i] - m_) : 0.f;
    }
    float ps = ((p[0] + p[1]) + (p[2] + p[3])) + ((p[4] + p[5]) + (p[6] + p[7]))
             + ((p[8] + p[9]) + (p[10] + p[11])) + ((p[12] + p[13]) + (p[14] + p[15]));
    ps += __shfl_xor(ps, 16);
    ps += __shfl_xor(ps, 32);
    l_ += ps;

    // P (fp32, lane q=llo, keys kb4*16+lhi*4+j) -> wave-private LDS as bf16
#pragma unroll
    for (int kb4 = 0; kb4 < 4; ++kb4) {
      uint d0 = (uint)f2b(p[kb4 * 4 + 0]) | ((uint)f2b(p[kb4 * 4 + 1]) << 16);
      uint d1 = (uint)f2b(p[kb4 * 4 + 2]) | ((uint)f2b(p[kb4 * 4 + 3]) << 16);
      sPd[wid][llo * 36 + kb4 * 8 + lhi * 2]     = d0;
      sPd[wid][llo * 36 + kb4 * 8 + lhi * 2 + 1] = d1;
    }
    bf16x8 pf0 = *(const bf16x8*)&sPd[wid][llo * 36 + lhi * 4];        // keys 0..31
    bf16x8 pf1 = *(const bf16x8*)&sPd[wid][llo * 36 + 16 + lhi * 4];   // keys 32..63

    // O^T += V^T P^T : o row = d offset, col = q
    __builtin_amdgcn_s_setprio(1);
#pragma unroll
    for (int nf = 0; nf < 4; ++nf) {
      bf16x8 vf0 = *(const bf16x8*)&sV[(nf * 16 + llo) * 72 + lhi * 8];
      bf16x8 vf1 = *(const bf16x8*)&sV[(nf * 16 + llo) * 72 + 32 + lhi * 8];
      o[nf] = __builtin_amdgcn_mfma_f32_16x16x32_bf16(vf0, pf0, o[nf], 0, 0, 0);
      o[nf] = __builtin_amdgcn_mfma_f32_16x16x32_bf16(vf1, pf1, o[nf], 0, 0, 0);
    }
    __builtin_amdgcn_s_setprio(0);
  }

  float inv = 1.f / l_;
  int qi = qw0 + llo;
  size_t obase = ((size_t)b * 2048 + qi) * 1024 + (bh & 15) * 64 + lhi * 4;
#pragma unroll
  for (int nf = 0; nf < 4; ++nf) {
    float4 st = make_float4(o[nf][0] * inv, o[nf][1] * inv, o[nf][2] * inv, o[nf][3] * inv);
    *(float4*)&out[obase + nf * 16] = st;
  }
}

// ---------------------------------------------------------------------------
extern "C" void kernel_launch(void* const* d_in, const int* in_sizes, int n_in,
                              void* d_out, int out_size, void* d_ws, size_t ws_size,
                              hipStream_t stream) {
  const float* x  = (const float*)d_in[0];
  const float* wq = (const float*)d_in[1];
  const float* bq = (const float*)d_in[2];
  const float* wk = (const float*)d_in[3];
  const float* bk = (const float*)d_in[4];
  const float* wv = (const float*)d_in[5];
  const float* bv = (const float*)d_in[6];
  const int* kmask = (const int*)d_in[7];
  const int* whist = (const int*)d_in[8];
  float* out = (float*)d_out;

  char* ws = (char*)d_ws;
  ushort* xb  = (ushort*)(ws);                       // [4096][1024] bf16   8 MB
  ushort* wt  = (ushort*)(ws + (8ull  << 20));       // [3072][1024] bf16   6 MB
  ushort* C   = (ushort*)(ws + (14ull << 20));       // [4096][3072] bf16  24 MB
  ushort* qb  = (ushort*)(ws + (38ull << 20));       // [32][2048][64]      8 MB
  ushort* kb  = (ushort*)(ws + (46ull << 20));       // [32][2048][64]      8 MB
  ushort* vt  = (ushort*)(ws + (54ull << 20));       // [32][64][2048]      8 MB
  float2* tab = (float2*)(ws + (62ull << 20));       // [2048][32] float2  .5 MB

  prep_x_kernel<<<4096, 256, 0, stream>>>(x, xb);
  prep_w_kernel<<<dim3(32, 32, 3), dim3(32, 32, 1), 0, stream>>>(wq, wk, wv, wt);
  rope_tab_kernel<<<256, 256, 0, stream>>>(tab);
  qkv_gemm_kernel<<<256, 512, 0, stream>>>(xb, wt, C);
  epi_qk_kernel<<<2048, 256, 0, stream>>>(C, bq, bk, tab, qb, kb);
  epi_v_kernel<<<dim3(32, 32), 256, 0, stream>>>(C, bv, vt);
  attn_kernel<<<1024, 256, 0, stream>>>(qb, kb, vt, kmask, whist, out);
}

// Round 5
// 89.586 us; speedup vs baseline: 1.3567x; 1.0335x over previous
//
#include <hip/hip_runtime.h>
#include <hip/hip_bf16.h>
#include <stdint.h>

// ---------------------------------------------------------------------------
// MultiHeadedSelfAttention: x[2,2048,1024] -> out[2,2048,1024] (fp32)
// prep(bf16, W^T, rope table) -> fused QKV GEMM (256x192 tile, quad-buffered
// LDS, ONE barrier per K-step, counted vmcnt) -> bias+RoPE epilogues ->
// banded flash attention (QBLK=128, 8 waves, swapped-operand MFMA).
// ---------------------------------------------------------------------------

typedef __attribute__((ext_vector_type(8))) short bf16x8;
typedef __attribute__((ext_vector_type(4))) short bf16x4;
typedef __attribute__((ext_vector_type(4))) float f32x4;

#define DEV __device__ __forceinline__

DEV ushort f2b(float f) {               // fp32 -> bf16 bits, round-nearest-even
  union { float f; uint32_t u; } v; v.f = f;
  uint32_t r = v.u + 0x7FFFu + ((v.u >> 16) & 1u);
  return (ushort)(r >> 16);
}
DEV float b2f(ushort u) {
  union { uint32_t u; float f; } v; v.u = ((uint32_t)u) << 16;
  return v.f;
}

DEV void gload_lds16(const void* g, void* l) {
  __builtin_amdgcn_global_load_lds((const __attribute__((address_space(1))) void*)g,
                                   (__attribute__((address_space(3))) void*)l,
                                   16, 0, 0);
}

// ---------------------------------------------------------------------------
__global__ __launch_bounds__(256) void prep_x_kernel(const float* __restrict__ x,
                                                     ushort* __restrict__ xb) {
  int t = blockIdx.x * 256 + threadIdx.x;
  float4 v = ((const float4*)x)[t];
  bf16x4 o;
  o[0] = (short)f2b(v.x); o[1] = (short)f2b(v.y);
  o[2] = (short)f2b(v.z); o[3] = (short)f2b(v.w);
  *(bf16x4*)&xb[(size_t)t * 4] = o;
}

__global__ void prep_w_kernel(const float* __restrict__ wq, const float* __restrict__ wk,
                              const float* __restrict__ wv, ushort* __restrict__ wt) {
  __shared__ float tile[32][33];
  int which = blockIdx.z;
  const float* w = which == 0 ? wq : (which == 1 ? wk : wv);
  int n0 = blockIdx.x * 32, k0 = blockIdx.y * 32;
  tile[threadIdx.y][threadIdx.x] = w[(size_t)(k0 + threadIdx.y) * 1024 + n0 + threadIdx.x];
  __syncthreads();
  wt[((size_t)which * 1024 + n0 + threadIdx.y) * 1024 + k0 + threadIdx.x] =
      f2b(tile[threadIdx.x][threadIdx.y]);
}

__global__ __launch_bounds__(256) void rope_tab_kernel(float2* __restrict__ tab) {
  int t = blockIdx.x * 256 + threadIdx.x;          // 65536
  int i = t & 31, s = t >> 5;
  float theta = powf(10000.0f, -(float)i / 32.0f);
  float ang = (float)s * theta;
  tab[t] = make_float2(cosf(ang), sinf(ang));
}

// ---------------------------------------------------------------------------
// QKV GEMM: A = xb [4096][1024], Bt = wt [3072][1024] -> C bf16 [4096][3072]
// 256x192 tile, BK=32, 8 waves (2Mx4N), quad-buffered LDS (128 KiB),
// ONE s_barrier per K-step, counted vmcnt (loads span 3 K-steps).
__global__ __launch_bounds__(512, 2) void qkv_gemm_kernel(const ushort* __restrict__ A,
                                                          const ushort* __restrict__ Bt,
                                                          ushort* __restrict__ C) {
  const int K = 1024, N = 3072;
  __shared__ alignas(16) ushort sS[4][2][256 * 32];   // [buf][A/B][256 rows][32 k]

  int tid = threadIdx.x;
  int lane = tid & 63;
  int lhi = lane >> 4, llo = lane & 15;
  int wid = tid >> 6;
  int wr = wid >> 2, wc = wid & 3;                    // 2M x 4N waves

  int id = blockIdx.x;
  int wg = (id & 7) * 32 + (id >> 3);                 // XCD-grouped (256 = 8 x 32)
  int bm = wg >> 4, bn = wg & 15;                     // 16 x 16 tiles

  const ushort* Abase = A + (size_t)bm * 256 * K;
  const ushort* Bbase = Bt + (size_t)bn * 192 * K;

  f32x4 acc[8][3];
#pragma unroll
  for (int mf = 0; mf < 8; ++mf)
#pragma unroll
    for (int nf = 0; nf < 3; ++nf) acc[mf][nf] = (f32x4){0.f, 0.f, 0.f, 0.f};

  auto stage = [&](int kt, int bb) {                  // 4 gload_lds per thread
    int k0 = kt * 32;
#pragma unroll
    for (int c = 0; c < 2; ++c) {
      int idx = c * 512 + tid;                        // [0,1024): A rows 0..255
      int rowA = idx >> 2, col = (idx & 3) * 8;
      gload_lds16(Abase + (size_t)rowA * K + k0 + col, &sS[bb][0][idx * 8]);
      int rowB = rowA < 192 ? rowA : 191;             // clamp (rows 192..255 unused)
      gload_lds16(Bbase + (size_t)rowB * K + k0 + col, &sS[bb][1][idx * 8]);
    }
  };

  stage(0, 0); stage(1, 1); stage(2, 2);              // 12 loads in flight

  for (int kt = 0; kt < 32; ++kt) {
    // wait for tile kt (own oldest 4 loads); tiles kt+1, kt+2 stay in flight
    if (kt <= 29)      asm volatile("s_waitcnt vmcnt(8)" ::: "memory");
    else if (kt == 30) asm volatile("s_waitcnt vmcnt(4)" ::: "memory");
    else               asm volatile("s_waitcnt vmcnt(0)" ::: "memory");
    __builtin_amdgcn_sched_barrier(0);
    __builtin_amdgcn_s_barrier();   // tile kt resident everywhere; buf (kt-1)%4 free
    __builtin_amdgcn_sched_barrier(0);

    if (kt + 3 < 32) stage(kt + 3, (kt + 3) & 3);     // refill freed buffer early
    __builtin_amdgcn_sched_barrier(0);

    int bb = kt & 3;
    const ushort* pA = sS[bb][0];
    const ushort* pB = sS[bb][1];
    bf16x8 af[8], bfr[3];
#pragma unroll
    for (int mf = 0; mf < 8; ++mf)
      af[mf] = *(const bf16x8*)&pA[(wr * 128 + mf * 16 + llo) * 32 + lhi * 8];
#pragma unroll
    for (int nf = 0; nf < 3; ++nf)
      bfr[nf] = *(const bf16x8*)&pB[(wc * 48 + nf * 16 + llo) * 32 + lhi * 8];
    __builtin_amdgcn_s_setprio(1);
#pragma unroll
    for (int mf = 0; mf < 8; ++mf)
#pragma unroll
      for (int nf = 0; nf < 3; ++nf)
        acc[mf][nf] = __builtin_amdgcn_mfma_f32_16x16x32_bf16(af[mf], bfr[nf], acc[mf][nf], 0, 0, 0);
    __builtin_amdgcn_s_setprio(0);
  }

#pragma unroll
  for (int mf = 0; mf < 8; ++mf)
#pragma unroll
    for (int nf = 0; nf < 3; ++nf)
#pragma unroll
      for (int j = 0; j < 4; ++j) {
        int row = bm * 256 + wr * 128 + mf * 16 + lhi * 4 + j;
        int col = bn * 192 + wc * 48 + nf * 16 + llo;
        C[(size_t)row * N + col] = f2b(acc[mf][nf][j]);
      }
}

// ---------------------------------------------------------------------------
// epilogue: bias + RoPE, vectorized 8 elems/thread. q pre-scaled by 0.125.
__global__ __launch_bounds__(256) void epi_qk_kernel(const ushort* __restrict__ C,
    const float* __restrict__ bq, const float* __restrict__ bk,
    const float2* __restrict__ tab,
    ushort* __restrict__ qb, ushort* __restrict__ kb) {
  int t = blockIdx.x * 256 + threadIdx.x;          // 4096*128
  int m = t >> 7, pp = (t & 127) << 3;
  int s = m & 2047;
  int h = pp >> 6, i0 = (pp & 63) >> 1;
  size_t crow = (size_t)m * 3072;
  bf16x8 qv = *(const bf16x8*)&C[crow + pp];
  bf16x8 kv = *(const bf16x8*)&C[crow + 1024 + pp];
  float4 bq0 = *(const float4*)&bq[pp], bq1 = *(const float4*)&bq[pp + 4];
  float4 bk0 = *(const float4*)&bk[pp], bk1 = *(const float4*)&bk[pp + 4];
  float4 cs01 = *(const float4*)&tab[s * 32 + i0];
  float4 cs23 = *(const float4*)&tab[s * 32 + i0 + 2];
  float cth[4] = {cs01.x, cs01.z, cs23.x, cs23.z};
  float sth[4] = {cs01.y, cs01.w, cs23.y, cs23.w};
  float bqa[8] = {bq0.x, bq0.y, bq0.z, bq0.w, bq1.x, bq1.y, bq1.z, bq1.w};
  float bka[8] = {bk0.x, bk0.y, bk0.z, bk0.w, bk1.x, bk1.y, bk1.z, bk1.w};
  bf16x8 qo, ko;
#pragma unroll
  for (int e = 0; e < 4; ++e) {
    float t0 = b2f((ushort)qv[2 * e])     + bqa[2 * e];
    float t1 = b2f((ushort)qv[2 * e + 1]) + bqa[2 * e + 1];
    qo[2 * e]     = (short)f2b((t0 * cth[e] - t1 * sth[e]) * 0.125f);
    qo[2 * e + 1] = (short)f2b((t1 * cth[e] + t0 * sth[e]) * 0.125f);
    float u0 = b2f((ushort)kv[2 * e])     + bka[2 * e];
    float u1 = b2f((ushort)kv[2 * e + 1]) + bka[2 * e + 1];
    ko[2 * e]     = (short)f2b(u0 * cth[e] - u1 * sth[e]);
    ko[2 * e + 1] = (short)f2b(u1 * cth[e] + u0 * sth[e]);
  }
  int bh = (m >> 11) * 16 + h;
  size_t ooff = ((size_t)bh * 2048 + s) * 64 + (pp & 63);
  *(bf16x8*)&qb[ooff] = qo;
  *(bf16x8*)&kb[ooff] = ko;
}

// epilogue: bias + transpose for v -> vt [32][64][2048] bf16
__global__ __launch_bounds__(256) void epi_v_kernel(const ushort* __restrict__ C,
    const float* __restrict__ bv, ushort* __restrict__ vt) {
  __shared__ float lv[64][65];
  int bh = blockIdx.y; int h = bh & 15;
  int s0 = blockIdx.x * 64;
  int tid = threadIdx.x;
  size_t mbase = (size_t)(bh >> 4) * 2048 + s0;
#pragma unroll
  for (int ph = 0; ph < 2; ++ph) {
    int idx = ph * 256 + tid;
    int row = idx >> 3, col = (idx & 7) * 8;
    bf16x8 v = *(const bf16x8*)&C[(mbase + row) * 3072 + 2048 + h * 64 + col];
#pragma unroll
    for (int e = 0; e < 8; ++e) lv[row][col + e] = b2f((ushort)v[e]);
  }
  __syncthreads();
#pragma unroll
  for (int ph = 0; ph < 2; ++ph) {
    int idx = ph * 256 + tid;
    int hd = idx >> 3, s8 = (idx & 7) * 8;
    float bias = bv[h * 64 + hd];
    bf16x8 o;
#pragma unroll
    for (int e = 0; e < 8; ++e) o[e] = (short)f2b(lv[s8 + e][hd] + bias);
    *(bf16x8*)&vt[((size_t)bh * 64 + hd) * 2048 + s0 + s8] = o;
  }
}

// ---------------------------------------------------------------------------
// banded flash attention, swapped-operand form. QBLK=128 (8 waves x 16 rows),
// KVBLK=64, reg-staged dbuf, per-wave active-window guard, XCD-grouped bh.
__global__ __launch_bounds__(512) void attn_kernel(
    const ushort* __restrict__ qb, const ushort* __restrict__ kb,
    const ushort* __restrict__ vt, const int* __restrict__ kmask,
    const int* __restrict__ whist, float* __restrict__ out) {
  __shared__ alignas(16) ushort sK[64 * 64];       // [64 keys][64 hd], XOR-swizzled
  __shared__ alignas(16) ushort sV[64 * 72];       // [64 d][64 keys], pitch 72
  __shared__ alignas(16) uint   sPd[8][16 * 36];   // per-wave P [16 q][64 k] bf16, pitch 36 dw

  int tid = threadIdx.x;
  int lane = tid & 63, wid = tid >> 6;             // 8 waves
  int lhi = lane >> 4, llo = lane & 15;

  int id = blockIdx.x;                             // 512 blocks
  int xcd = id & 7, sub = id >> 3;                 // T1: same-bh blocks per XCD
  int bh = xcd * 4 + (sub >> 4);
  int qtile = sub & 15;
  int b = bh >> 4;
  int q0 = qtile * 128;
  int qw0 = q0 + wid * 16;
  int W = *whist;

  const ushort* qptr = qb + (size_t)bh * 2048 * 64;
  const ushort* kptr = kb + (size_t)bh * 2048 * 64;
  const ushort* vptr = vt + (size_t)bh * 64 * 2048;
  const int* mrow = kmask + b * 2048;

  bf16x8 qf0, qf1;                                 // Q frag, q = llo, hd halves
  {
    size_t base = (size_t)(qw0 + llo) * 64 + lhi * 8;
    qf0 = *(const bf16x8*)&qptr[base];
    qf1 = *(const bf16x8*)&qptr[base + 32];
  }

  float m_ = -1e30f, l_ = 0.f;                     // lane-local: q = qw0 + llo
  f32x4 o[4];                                      // O^T: d = nf*16 + lhi*4 + j, q = llo
#pragma unroll
  for (int nf = 0; nf < 4; ++nf) o[nf] = (f32x4){0.f, 0.f, 0.f, 0.f};

  int lo = q0 - (W - 1); if (lo < 0) lo = 0;
  int jt0 = lo & ~63;
  int nt = ((q0 + 128) - jt0) >> 6;                // tiles covering all 128 q rows

  bf16x8 kreg, vreg;
  int mreg;
  int srow = tid >> 3, sslot = tid & 7;            // 64 rows x 8 slots

  auto load_tile = [&](int jt) {                   // global -> regs (prefetch)
    kreg = *(const bf16x8*)&kptr[(size_t)(jt + srow) * 64 + sslot * 8];
    vreg = *(const bf16x8*)&vptr[(size_t)srow * 2048 + jt + sslot * 8];
    mreg = mrow[jt + lane];
  };

  load_tile(jt0);
  for (int it = 0; it < nt; ++it) {
    int jt = jt0 + it * 64;
    __syncthreads();                               // prev tile's LDS reads done
    *(bf16x8*)&sK[srow * 64 + ((sslot ^ (srow & 7)) * 8)] = kreg;
    *(bf16x8*)&sV[srow * 72 + sslot * 8] = vreg;
    unsigned long long pm = __ballot(mreg != 0);   // padded-key bitmask (wave-uniform)
    if (it + 1 < nt) load_tile(jt + 64);           // prefetch hides under compute
    __syncthreads();                               // LDS tile visible

    // per-wave window guard (wave-uniform; barriers stay outside)
    bool active = (jt <= qw0 + 15) && (jt + 63 >= qw0 - W + 1);
    if (active) {
      // S^T = K Q^T : sc[kb4] row = key offset (lhi*4+j), col = q (llo)
      f32x4 sc[4];
#pragma unroll
      for (int kb4 = 0; kb4 < 4; ++kb4) sc[kb4] = (f32x4){0.f, 0.f, 0.f, 0.f};
      __builtin_amdgcn_s_setprio(1);
#pragma unroll
      for (int ks = 0; ks < 2; ++ks) {
        bf16x8 qq = ks ? qf1 : qf0;
#pragma unroll
        for (int kb4 = 0; kb4 < 4; ++kb4) {
          int r = kb4 * 16 + llo;
          bf16x8 kf = *(const bf16x8*)&sK[r * 64 + (((ks * 4 + lhi) ^ (r & 7)) * 8)];
          sc[kb4] = __builtin_amdgcn_mfma_f32_16x16x32_bf16(kf, qq, sc[kb4], 0, 0, 0);
        }
      }
      __builtin_amdgcn_s_setprio(0);

      bool fast = (jt + 63 <= qw0) && (jt >= qw0 + 16 - W) && (pm == 0ull);
      float s[16];
      bool ok[16];
      if (fast) {
#pragma unroll
        for (int kb4 = 0; kb4 < 4; ++kb4)
#pragma unroll
          for (int j = 0; j < 4; ++j) s[kb4 * 4 + j] = sc[kb4][j];
      } else {
        int qi = qw0 + llo;
#pragma unroll
        for (int kb4 = 0; kb4 < 4; ++kb4) {
          uint nib = (uint)(pm >> (kb4 * 16 + lhi * 4)) & 0xFu;
#pragma unroll
          for (int j = 0; j < 4; ++j) {
            int key = jt + kb4 * 16 + lhi * 4 + j;
            bool k_ok = (key <= qi) && (qi - key < W) && !((nib >> j) & 1u);
            ok[kb4 * 4 + j] = k_ok;
            s[kb4 * 4 + j] = k_ok ? sc[kb4][j] : -1e30f;
          }
        }
      }

      // lane-local max over 16 + 2 shuffles across lhi groups
      float t01 = fmaxf(s[0], s[1]),  t23 = fmaxf(s[2], s[3]);
      float t45 = fmaxf(s[4], s[5]),  t67 = fmaxf(s[6], s[7]);
      float t89 = fmaxf(s[8], s[9]),  tab_ = fmaxf(s[10], s[11]);
      float tcd = fmaxf(s[12], s[13]), tef = fmaxf(s[14], s[15]);
      float t = fmaxf(fmaxf(fmaxf(t01, t23), fmaxf(t45, t67)),
                      fmaxf(fmaxf(t89, tab_), fmaxf(tcd, tef)));
      t = fmaxf(t, __shfl_xor(t, 16));
      t = fmaxf(t, __shfl_xor(t, 32));

      if (t > m_ + 8.f) {                          // defer-max (T13, THR=8)
        float fac = __expf(m_ - t);
        l_ *= fac;
#pragma unroll
        for (int nf = 0; nf < 4; ++nf) o[nf] *= fac;
        m_ = t;
      }

      float p[16];
      if (fast) {
#pragma unroll
        for (int i = 0; i < 16; ++i) p[i] = __expf(s[i] - m_);
      } else {                                     // masked p exactly 0
#pragma unroll
        for (int i = 0; i < 16; ++i) p[i] = ok[i] ? __expf(s[i] - m_) : 0.f;
      }
      float ps = ((p[0] + p[1]) + (p[2] + p[3])) + ((p[4] + p[5]) + (p[6] + p[7]))
               + ((p[8] + p[9]) + (p[10] + p[11])) + ((p[12] + p[13]) + (p[14] + p[15]));
      ps += __shfl_xor(ps, 16);
      ps += __shfl_xor(ps, 32);
      l_ += ps;

      // P (fp32, lane q=llo, keys kb4*16+lhi*4+j) -> wave-private LDS as bf16
#pragma unroll
      for (int kb4 = 0; kb4 < 4; ++kb4) {
        uint d0 = (uint)f2b(p[kb4 * 4 + 0]) | ((uint)f2b(p[kb4 * 4 + 1]) << 16);
        uint d1 = (uint)f2b(p[kb4 * 4 + 2]) | ((uint)f2b(p[kb4 * 4 + 3]) << 16);
        sPd[wid][llo * 36 + kb4 * 8 + lhi * 2]     = d0;
        sPd[wid][llo * 36 + kb4 * 8 + lhi * 2 + 1] = d1;
      }
      bf16x8 pf0 = *(const bf16x8*)&sPd[wid][llo * 36 + lhi * 4];        // keys 0..31
      bf16x8 pf1 = *(const bf16x8*)&sPd[wid][llo * 36 + 16 + lhi * 4];   // keys 32..63

      // O^T += V^T P^T : o row = d offset, col = q
      __builtin_amdgcn_s_setprio(1);
#pragma unroll
      for (int nf = 0; nf < 4; ++nf) {
        bf16x8 vf0 = *(const bf16x8*)&sV[(nf * 16 + llo) * 72 + lhi * 8];
        bf16x8 vf1 = *(const bf16x8*)&sV[(nf * 16 + llo) * 72 + 32 + lhi * 8];
        o[nf] = __builtin_amdgcn_mfma_f32_16x16x32_bf16(vf0, pf0, o[nf], 0, 0, 0);
        o[nf] = __builtin_amdgcn_mfma_f32_16x16x32_bf16(vf1, pf1, o[nf], 0, 0, 0);
      }
      __builtin_amdgcn_s_setprio(0);
    }
  }

  float inv = 1.f / l_;
  int qi = qw0 + llo;
  size_t obase = ((size_t)b * 2048 + qi) * 1024 + (bh & 15) * 64 + lhi * 4;
#pragma unroll
  for (int nf = 0; nf < 4; ++nf) {
    float4 st = make_float4(o[nf][0] * inv, o[nf][1] * inv, o[nf][2] * inv, o[nf][3] * inv);
    *(float4*)&out[obase + nf * 16] = st;
  }
}

// ---------------------------------------------------------------------------
extern "C" void kernel_launch(void* const* d_in, const int* in_sizes, int n_in,
                              void* d_out, int out_size, void* d_ws, size_t ws_size,
                              hipStream_t stream) {
  const float* x  = (const float*)d_in[0];
  const float* wq = (const float*)d_in[1];
  const float* bq = (const float*)d_in[2];
  const float* wk = (const float*)d_in[3];
  const float* bk = (const float*)d_in[4];
  const float* wv = (const float*)d_in[5];
  const float* bv = (const float*)d_in[6];
  const int* kmask = (const int*)d_in[7];
  const int* whist = (const int*)d_in[8];
  float* out = (float*)d_out;

  char* ws = (char*)d_ws;
  ushort* xb  = (ushort*)(ws);                       // [4096][1024] bf16   8 MB
  ushort* wt  = (ushort*)(ws + (8ull  << 20));       // [3072][1024] bf16   6 MB
  ushort* C   = (ushort*)(ws + (14ull << 20));       // [4096][3072] bf16  24 MB
  ushort* qb  = (ushort*)(ws + (38ull << 20));       // [32][2048][64]      8 MB
  ushort* kb  = (ushort*)(ws + (46ull << 20));       // [32][2048][64]      8 MB
  ushort* vt  = (ushort*)(ws + (54ull << 20));       // [32][64][2048]      8 MB
  float2* tab = (float2*)(ws + (62ull << 20));       // [2048][32] float2  .5 MB

  prep_x_kernel<<<4096, 256, 0, stream>>>(x, xb);
  prep_w_kernel<<<dim3(32, 32, 3), dim3(32, 32, 1), 0, stream>>>(wq, wk, wv, wt);
  rope_tab_kernel<<<256, 256, 0, stream>>>(tab);
  qkv_gemm_kernel<<<256, 512, 0, stream>>>(xb, wt, C);
  epi_qk_kernel<<<2048, 256, 0, stream>>>(C, bq, bk, tab, qb, kb);
  epi_v_kernel<<<dim3(32, 32), 256, 0, stream>>>(C, bv, vt);
  attn_kernel<<<512, 512, 0, stream>>>(qb, kb, vt, kmask, whist, out);
}